// Round 9
// baseline (227.305 us; speedup 1.0000x reference)
//
#include <hip/hip_runtime.h>
#include <hip/hip_bf16.h>

// Self-attention: B=4, S=2048, D=768, fp32 in/out, bf16 MFMA internally.
// R9: double-buffered LDS K-loop with ONE barrier per iteration and the
// async stage of k+1 issued at the TOP of the body (into the other buffer,
// so no WAR barrier needed). The vmcnt(0) drain at the end-of-iter barrier
// now sits a full body (~350 cyc of ds_read+MFMA) after load issue, vs
// ~155 cyc in R6/R8 — the exposed-latency convoy (MFMA 21-24%, nothing
// saturated) was the diagnosed limiter. Fragments: R6's 16x16x32 pattern
// (measured 0 bank conflicts; R8's 32x32 geometry re-introduced 4 cyc/read).
// ws: Xb | WqT WkT WvT | Qb Kb Vt | Es

typedef __attribute__((ext_vector_type(8))) short short8;
typedef __attribute__((ext_vector_type(4))) short short4v;
typedef __attribute__((ext_vector_type(4))) float float4v;

static constexpr int B_ = 4, S_ = 2048, D_ = 768;
static constexpr int MS = B_ * S_;  // 8192

__device__ inline short f2bf(float f) {
  __hip_bfloat16 h = __float2bfloat16(f);
  union { __hip_bfloat16 h; short s; } u; u.h = h; return u.s;
}

typedef const __attribute__((address_space(1))) unsigned int g_u32;
typedef __attribute__((address_space(3))) unsigned int l_u32;

__device__ __forceinline__ void glds16(const short* g, short* l) {
  __builtin_amdgcn_global_load_lds((g_u32*)g, (l_u32*)l, 16, 0, 0);
}

__global__ __launch_bounds__(256)
void cast_f32_bf16(const float* __restrict__ x, short* __restrict__ y, int n) {
  int i = (blockIdx.x * 256 + threadIdx.x) * 4;
  if (i + 3 < n) {
    float4v v = *(const float4v*)(x + i);
    short4v o;
    o.x = f2bf(v.x); o.y = f2bf(v.y); o.z = f2bf(v.z); o.w = f2bf(v.w);
    *(short4v*)(y + i) = o;
  }
}

// T[e][d] = (bf16) W[d][e], for three 768x768 matrices
__global__ void transpose_cast_w(const float* __restrict__ W0, const float* __restrict__ W1,
                                 const float* __restrict__ W2,
                                 short* __restrict__ T0, short* __restrict__ T1,
                                 short* __restrict__ T2) {
  const float* W = blockIdx.z == 0 ? W0 : (blockIdx.z == 1 ? W1 : W2);
  short* T = blockIdx.z == 0 ? T0 : (blockIdx.z == 1 ? T1 : T2);
  __shared__ float tile[32][33];
  int bx = blockIdx.x * 32, by = blockIdx.y * 32;
  int tx = threadIdx.x, ty = threadIdx.y;
  for (int r = ty; r < 32; r += 8)
    tile[r][tx] = W[(by + r) * D_ + bx + tx];
  __syncthreads();
  for (int r = ty; r < 32; r += 8)
    T[(bx + r) * D_ + by + tx] = f2bf(tile[tx][r]);
}

// C = A @ Bt^T over K (K%64==0), batched via blockIdx.z. 128x128 block,
// 4 waves 2x2, wave tile 64x64 of 4x4 16x16x32 MFMAs. BK=64, double-buffered.
// LDS rows 128 B = 8 x 16-B chunks, XOR-swizzled at the global source:
// chunk g of row r staged at position g^(r&7); fragment chunk c reads c^(R&7).
// K-loop: stage(k+1 -> other buf) -> ds_read frags(cur) -> MFMA -> barrier.
// EPI 0: QKV tri-output: n<768 -> Qb+bq ; <1536 -> Kb+bk ; else Vt transposed +bv
// EPI 2: bf16 out = exp(acc*scale)
// EPI 3: fp32 out = acc / rowsum[m], rowsum via ones-MFMA in-loop
template<int EPI>
__global__ __launch_bounds__(256)
void gemm_bt(const short* __restrict__ A, const short* __restrict__ Bt,
             void* __restrict__ C0v, short* __restrict__ C1, short* __restrict__ C2,
             const float* __restrict__ bias0, const float* __restrict__ bias1,
             const float* __restrict__ bias2,
             int K, int lda, int ldb, int ldc,
             long sA, long sB, long sC, float scale) {
  const int b = blockIdx.z;
  A += (long)b * sA;
  Bt += (long)b * sB;
  float* Cf = (float*)C0v + (long)b * sC;
  short* Cs = (short*)C0v + (long)b * sC;

  __shared__ short As[2][128 * 64];   // ping-pong [128 rows][64 shorts = 128 B]
  __shared__ short Bs[2][128 * 64];   // 64 KB total

  const int t = threadIdx.x;
  const int wave = t >> 6, lane = t & 63;
  const int lane16 = lane & 15, q = lane >> 4;
  const int m0 = blockIdx.y * 128, n0 = blockIdx.x * 128;
  const int wm = (wave >> 1) * 64, wn = (wave & 1) * 64;
  const int rsub = lane >> 3;          // staging: row within 8-row wave-instr
  const int g = (lane & 7) ^ rsub;     // staging: swizzled source chunk

  auto stage = [&](int kk, int p) {
#pragma unroll
    for (int i = wave; i < 16; i += 4)
      glds16(A + (long)(m0 + i * 8 + rsub) * lda + kk + g * 8, &As[p][i * 512]);
#pragma unroll
    for (int i = wave; i < 16; i += 4)
      glds16(Bt + (long)(n0 + i * 8 + rsub) * ldb + kk + g * 8, &Bs[p][i * 512]);
  };

  stage(0, 0);  // prologue

  float4v acc[4][4];
#pragma unroll
  for (int i = 0; i < 4; i++)
#pragma unroll
    for (int j = 0; j < 4; j++) acc[i][j] = {0.f, 0.f, 0.f, 0.f};

  float4v acc_rs[4];  // EPI==3 only; dead otherwise
#pragma unroll
  for (int i = 0; i < 4; i++) acc_rs[i] = {0.f, 0.f, 0.f, 0.f};
  short8 ones;
#pragma unroll
  for (int e = 0; e < 8; e++) ones[e] = (short)0x3F80;  // bf16 1.0

  __syncthreads();  // drain stage(0)

  const int nIter = K / 64;
  for (int it = 0; it < nIter; it++) {
    const int cur = it & 1;
    if (it + 1 < nIter) stage((it + 1) * 64, cur ^ 1);  // issue ASAP, other buf

    short8 af[2][4], bfr[2][4];
#pragma unroll
    for (int s = 0; s < 2; s++) {
#pragma unroll
      for (int i = 0; i < 4; i++) {
        int R = wm + i * 16 + lane16;
        af[s][i] = *(const short8*)&As[cur][R * 64 + (((s * 4 + q) ^ (R & 7)) * 8)];
      }
#pragma unroll
      for (int j = 0; j < 4; j++) {
        int R = wn + j * 16 + lane16;
        bfr[s][j] = *(const short8*)&Bs[cur][R * 64 + (((s * 4 + q) ^ (R & 7)) * 8)];
      }
    }

#pragma unroll
    for (int s = 0; s < 2; s++) {
#pragma unroll
      for (int i = 0; i < 4; i++) {
#pragma unroll
        for (int j = 0; j < 4; j++)
          acc[i][j] = __builtin_amdgcn_mfma_f32_16x16x32_bf16(af[s][i], bfr[s][j], acc[i][j], 0, 0, 0);
        if (EPI == 3)
          acc_rs[i] = __builtin_amdgcn_mfma_f32_16x16x32_bf16(af[s][i], ones, acc_rs[i], 0, 0, 0);
      }
    }

    // Single barrier: (a) drains this iter's stage(it+1) [vmcnt(0)] so next
    // iter can read it; (b) all waves done reading As[cur], so iter it+2's
    // staging may overwrite it.
    if (it + 1 < nIter) __syncthreads();
  }

#pragma unroll
  for (int i = 0; i < 4; i++) {
    int mrow = m0 + wm + i * 16 + q * 4;
    if (EPI == 0) {
#pragma unroll
      for (int j = 0; j < 4; j++) {
        int ncol = n0 + wn + j * 16 + lane16;   // tile-uniform branch: bounds %16
        if (ncol < 1536) {
          short* dst = ncol < 768 ? Cs : C1;
          const float* bs = ncol < 768 ? bias0 : bias1;
          int c = ncol < 768 ? ncol : ncol - 768;   // NOT `& 767` (768 != pow2)
#pragma unroll
          for (int rr = 0; rr < 4; rr++)
            dst[(long)(mrow + rr) * 768 + c] = f2bf(acc[i][j][rr] + bs[c]);
        } else {
          int e = ncol - 1536;
          float bv = bias2[e];
          short4v o;
#pragma unroll
          for (int rr = 0; rr < 4; rr++) o[rr] = f2bf(acc[i][j][rr] + bv);
          *(short4v*)&C2[(long)e * MS + mrow] = o;   // Vt[e][m], 8-B store
        }
      }
    } else if (EPI == 2) {
#pragma unroll
      for (int j = 0; j < 4; j++) {
        int ncol = n0 + wn + j * 16 + lane16;
#pragma unroll
        for (int rr = 0; rr < 4; rr++)
          Cs[(long)(mrow + rr) * ldc + ncol] = f2bf(__expf(acc[i][j][rr] * scale));
      }
    } else {
#pragma unroll
      for (int rr = 0; rr < 4; rr++) {
        float inv = 1.0f / acc_rs[i][rr];   // rowsum(mrow+rr), same C/D slot
#pragma unroll
        for (int j = 0; j < 4; j++) {
          int ncol = n0 + wn + j * 16 + lane16;
          Cf[(long)(mrow + rr) * ldc + ncol] = acc[i][j][rr] * inv;
        }
      }
    }
  }
}

extern "C" void kernel_launch(void* const* d_in, const int* in_sizes, int n_in,
                              void* d_out, int out_size, void* d_ws, size_t ws_size,
                              hipStream_t stream) {
  const float* x  = (const float*)d_in[0];
  const float* Wq = (const float*)d_in[1];
  const float* bq = (const float*)d_in[2];
  const float* Wk = (const float*)d_in[3];
  const float* bk = (const float*)d_in[4];
  const float* Wv = (const float*)d_in[5];
  const float* bv = (const float*)d_in[6];
  float* out = (float*)d_out;

  short* Xb  = (short*)d_ws;                     // [8192][768]
  short* WqT = Xb + (long)MS * D_;               // [2304][768] = WqT||WkT||WvT
  short* WkT = WqT + (long)D_ * D_;
  short* WvT = WkT + (long)D_ * D_;
  short* Qb  = WvT + (long)D_ * D_;              // [8192][768]
  short* Kb  = Qb + (long)MS * D_;               // [8192][768]
  short* Vt  = Kb + (long)MS * D_;               // [768][8192]
  short* Es  = Vt + (long)MS * D_;               // [4][2048][2048] exp(scores)

  cast_f32_bf16<<<(MS * D_) / 1024, 256, 0, stream>>>(x, Xb, MS * D_);
  transpose_cast_w<<<dim3(24, 24, 3), dim3(32, 8), 0, stream>>>(Wq, Wk, Wv, WqT, WkT, WvT);

  // Q||K||Vt = Xb @ [WqT;WkT;WvT]^T + biases  (128x128 tiles, 18x64 = 1152 blk)
  gemm_bt<0><<<dim3(2304 / 128, MS / 128, 1), 256, 0, stream>>>(
      Xb, WqT, Qb, Kb, Vt, bq, bk, bv,
      D_, D_, D_, D_, 0, 0, 0, 1.0f);
  // Es[b,q,k] = exp((Qb[b] @ Kb[b]^T)/sqrt(D)) -> bf16  (16x16x4 = 1024 blk)
  gemm_bt<2><<<dim3(S_ / 128, S_ / 128, B_), 256, 0, stream>>>(
      Qb, Kb, Es, nullptr, nullptr, nullptr, nullptr, nullptr,
      D_, D_, D_, S_,
      (long)S_ * D_, (long)S_ * D_, (long)S_ * S_, 1.0f / sqrtf((float)D_));
  // O[b,q,e] = (Es[b] @ V[b]) / rowsum  -> fp32  (6x16x4 = 384 blk)
  gemm_bt<3><<<dim3(D_ / 128, S_ / 128, B_), 256, 0, stream>>>(
      Es, Vt, out, nullptr, nullptr, nullptr, nullptr, nullptr,
      S_, S_, MS, D_,
      (long)S_ * S_, (long)S_, (long)S_ * D_, 1.0f);
}

// Round 10
// 202.868 us; speedup vs baseline: 1.1205x; 1.1205x over previous
//
#include <hip/hip_runtime.h>
#include <hip/hip_bf16.h>

// Self-attention: B=4, S=2048, D=768, fp32 in/out, bf16 MFMA internally.
// R10: R6 inner loop retained verbatim (R7 no-LDS 2x worse; R8 32x32 neutral
// +conflicts; R9 dbuf regressed via occupancy loss — the 2-barrier BK=64
// single-buffer loop is the measured local optimum at these shapes).
// Changes: (1) PV uses 128x64 blocks -> 768 blocks = exactly 3/CU (was 384 =
// 1.5/CU, ~33% imbalance tax); (2) cast+transpose fused into one prep kernel
// (one fewer graph node/gap). ws: Xb | WqT WkT WvT | Qb Kb Vt | Es

typedef __attribute__((ext_vector_type(8))) short short8;
typedef __attribute__((ext_vector_type(4))) short short4v;
typedef __attribute__((ext_vector_type(4))) float float4v;

static constexpr int B_ = 4, S_ = 2048, D_ = 768;
static constexpr int MS = B_ * S_;  // 8192
static constexpr int CAST_BLOCKS = (MS * D_) / 1024;  // 6144

__device__ inline short f2bf(float f) {
  __hip_bfloat16 h = __float2bfloat16(f);
  union { __hip_bfloat16 h; short s; } u; u.h = h; return u.s;
}

typedef const __attribute__((address_space(1))) unsigned int g_u32;
typedef __attribute__((address_space(3))) unsigned int l_u32;

__device__ __forceinline__ void glds16(const short* g, short* l) {
  __builtin_amdgcn_global_load_lds((g_u32*)g, (l_u32*)l, 16, 0, 0);
}

// Fused prep: blocks [0, CAST_BLOCKS) cast x->bf16 (1024 elems each);
// blocks beyond transpose-cast the three weight matrices (32x32 tiles).
__global__ __launch_bounds__(256)
void prep(const float* __restrict__ x, short* __restrict__ y,
          const float* __restrict__ W0, const float* __restrict__ W1,
          const float* __restrict__ W2,
          short* __restrict__ T0, short* __restrict__ T1, short* __restrict__ T2) {
  int bid = blockIdx.x;
  int t = threadIdx.x;
  if (bid < CAST_BLOCKS) {
    int i = (bid * 256 + t) * 4;
    float4v v = *(const float4v*)(x + i);
    short4v o;
    o.x = f2bf(v.x); o.y = f2bf(v.y); o.z = f2bf(v.z); o.w = f2bf(v.w);
    *(short4v*)(y + i) = o;
    return;
  }
  int b2 = bid - CAST_BLOCKS;          // [0, 24*24*3)
  int z = b2 / 576, rem = b2 - z * 576;
  int by = (rem / 24) * 32, bx = (rem % 24) * 32;
  const float* W = z == 0 ? W0 : (z == 1 ? W1 : W2);
  short* T = z == 0 ? T0 : (z == 1 ? T1 : T2);
  __shared__ float tile[32][33];
  int tx = t & 31, ty = t >> 5;        // 32 x 8
  for (int r = ty; r < 32; r += 8)
    tile[r][tx] = W[(by + r) * D_ + bx + tx];
  __syncthreads();
  for (int r = ty; r < 32; r += 8)
    T[(bx + r) * D_ + by + tx] = f2bf(tile[tx][r]);
}

// C = A @ Bt^T over K (K%64==0), batched via blockIdx.z.
// Block = 4 waves 2x2; wave tile (TM*16)x(TN*16); block (TM*32)x(TN*32). BK=64.
// LDS rows 128 B = 8 x 16-B chunks, XOR-swizzled at the global source:
// chunk g of row r staged at position g^(r&7); fragment chunk c reads c^(R&7).
// K-loop: B1(drain stage k) -> ds_read frags -> B2 -> glds stage k+1 -> MFMA.
// EPI 0: QKV tri-output: n<768 -> Qb+bq ; <1536 -> Kb+bk ; else Vt transposed +bv
// EPI 2: bf16 out = exp(acc*scale)
// EPI 3: fp32 out = acc / rowsum[m], rowsum via ones-MFMA in-loop
template<int EPI, int TM, int TN>
__global__ __launch_bounds__(256)
void gemm_bt(const short* __restrict__ A, const short* __restrict__ Bt,
             void* __restrict__ C0v, short* __restrict__ C1, short* __restrict__ C2,
             const float* __restrict__ bias0, const float* __restrict__ bias1,
             const float* __restrict__ bias2,
             int K, int lda, int ldb, int ldc,
             long sA, long sB, long sC, float scale) {
  constexpr int BMv = TM * 32, BNv = TN * 32;
  const int b = blockIdx.z;
  A += (long)b * sA;
  Bt += (long)b * sB;
  float* Cf = (float*)C0v + (long)b * sC;
  short* Cs = (short*)C0v + (long)b * sC;

  __shared__ short As[BMv * 64];   // [BM][64 shorts = 128 B]
  __shared__ short Bs[BNv * 64];

  const int t = threadIdx.x;
  const int wave = t >> 6, lane = t & 63;
  const int lane16 = lane & 15, q = lane >> 4;
  const int m0 = blockIdx.y * BMv, n0 = blockIdx.x * BNv;
  const int wm = (wave >> 1) * (TM * 16), wn = (wave & 1) * (TN * 16);
  const int rsub = lane >> 3;          // staging: row within 8-row wave-instr
  const int g = (lane & 7) ^ rsub;     // staging: swizzled source chunk

  auto stage = [&](int kk) {
#pragma unroll
    for (int i = wave; i < BMv / 8; i += 4)
      glds16(A + (long)(m0 + i * 8 + rsub) * lda + kk + g * 8, &As[i * 512]);
#pragma unroll
    for (int i = wave; i < BNv / 8; i += 4)
      glds16(Bt + (long)(n0 + i * 8 + rsub) * ldb + kk + g * 8, &Bs[i * 512]);
  };

  stage(0);  // prologue; acc zero-init overlaps with the loads

  float4v acc[TM][TN];
#pragma unroll
  for (int i = 0; i < TM; i++)
#pragma unroll
    for (int j = 0; j < TN; j++) acc[i][j] = {0.f, 0.f, 0.f, 0.f};

  float4v acc_rs[TM];  // EPI==3 only; dead otherwise
#pragma unroll
  for (int i = 0; i < TM; i++) acc_rs[i] = {0.f, 0.f, 0.f, 0.f};
  short8 ones;
#pragma unroll
  for (int e = 0; e < 8; e++) ones[e] = (short)0x3F80;  // bf16 1.0

  for (int k0 = 0; k0 < K; k0 += 64) {
    __syncthreads();  // B1: drains stage(k0) [vmcnt(0)] + wave sync

    short8 af[2][TM], bfr[2][TN];
#pragma unroll
    for (int s = 0; s < 2; s++) {
#pragma unroll
      for (int i = 0; i < TM; i++) {
        int R = wm + i * 16 + lane16;
        af[s][i] = *(const short8*)&As[R * 64 + (((s * 4 + q) ^ (R & 7)) * 8)];
      }
#pragma unroll
      for (int j = 0; j < TN; j++) {
        int R = wn + j * 16 + lane16;
        bfr[s][j] = *(const short8*)&Bs[R * 64 + (((s * 4 + q) ^ (R & 7)) * 8)];
      }
    }
    __syncthreads();  // B2: all waves done reading LDS

    if (k0 + 64 < K) stage(k0 + 64);  // async; overlaps the MFMAs below

#pragma unroll
    for (int s = 0; s < 2; s++) {
#pragma unroll
      for (int i = 0; i < TM; i++) {
#pragma unroll
        for (int j = 0; j < TN; j++)
          acc[i][j] = __builtin_amdgcn_mfma_f32_16x16x32_bf16(af[s][i], bfr[s][j], acc[i][j], 0, 0, 0);
        if (EPI == 3)
          acc_rs[i] = __builtin_amdgcn_mfma_f32_16x16x32_bf16(af[s][i], ones, acc_rs[i], 0, 0, 0);
      }
    }
  }

#pragma unroll
  for (int i = 0; i < TM; i++) {
    int mrow = m0 + wm + i * 16 + q * 4;
    if (EPI == 0) {
#pragma unroll
      for (int j = 0; j < TN; j++) {
        int ncol = n0 + wn + j * 16 + lane16;   // tile-uniform branch: bounds %16
        if (ncol < 1536) {
          short* dst = ncol < 768 ? Cs : C1;
          const float* bs = ncol < 768 ? bias0 : bias1;
          int c = ncol < 768 ? ncol : ncol - 768;   // NOT `& 767` (768 != pow2)
#pragma unroll
          for (int rr = 0; rr < 4; rr++)
            dst[(long)(mrow + rr) * 768 + c] = f2bf(acc[i][j][rr] + bs[c]);
        } else {
          int e = ncol - 1536;
          float bv = bias2[e];
          short4v o;
#pragma unroll
          for (int rr = 0; rr < 4; rr++) o[rr] = f2bf(acc[i][j][rr] + bv);
          *(short4v*)&C2[(long)e * MS + mrow] = o;   // Vt[e][m], 8-B store
        }
      }
    } else if (EPI == 2) {
#pragma unroll
      for (int j = 0; j < TN; j++) {
        int ncol = n0 + wn + j * 16 + lane16;
#pragma unroll
        for (int rr = 0; rr < 4; rr++)
          Cs[(long)(mrow + rr) * ldc + ncol] = f2bf(__expf(acc[i][j][rr] * scale));
      }
    } else {
#pragma unroll
      for (int rr = 0; rr < 4; rr++) {
        float inv = 1.0f / acc_rs[i][rr];   // rowsum(mrow+rr), same C/D slot
#pragma unroll
        for (int j = 0; j < TN; j++) {
          int ncol = n0 + wn + j * 16 + lane16;
          Cf[(long)(mrow + rr) * ldc + ncol] = acc[i][j][rr] * inv;
        }
      }
    }
  }
}

extern "C" void kernel_launch(void* const* d_in, const int* in_sizes, int n_in,
                              void* d_out, int out_size, void* d_ws, size_t ws_size,
                              hipStream_t stream) {
  const float* x  = (const float*)d_in[0];
  const float* Wq = (const float*)d_in[1];
  const float* bq = (const float*)d_in[2];
  const float* Wk = (const float*)d_in[3];
  const float* bk = (const float*)d_in[4];
  const float* Wv = (const float*)d_in[5];
  const float* bv = (const float*)d_in[6];
  float* out = (float*)d_out;

  short* Xb  = (short*)d_ws;                     // [8192][768]
  short* WqT = Xb + (long)MS * D_;               // [2304][768] = WqT||WkT||WvT
  short* WkT = WqT + (long)D_ * D_;
  short* WvT = WkT + (long)D_ * D_;
  short* Qb  = WvT + (long)D_ * D_;              // [8192][768]
  short* Kb  = Qb + (long)MS * D_;               // [8192][768]
  short* Vt  = Kb + (long)MS * D_;               // [768][8192]
  short* Es  = Vt + (long)MS * D_;               // [4][2048][2048] exp(scores)

  // fused cast + weight transpose: 6144 + 1728 blocks
  prep<<<CAST_BLOCKS + 24 * 24 * 3, 256, 0, stream>>>(
      x, Xb, Wq, Wk, Wv, WqT, WkT, WvT);

  // Q||K||Vt = Xb @ [WqT;WkT;WvT]^T + biases  (128x128 tiles, 18x64 = 1152 blk)
  gemm_bt<0, 4, 4><<<dim3(2304 / 128, MS / 128, 1), 256, 0, stream>>>(
      Xb, WqT, Qb, Kb, Vt, bq, bk, bv,
      D_, D_, D_, D_, 0, 0, 0, 1.0f);
  // Es[b,q,k] = exp((Qb[b] @ Kb[b]^T)/sqrt(D)) -> bf16  (16x16x4 = 1024 blk)
  gemm_bt<2, 4, 4><<<dim3(S_ / 128, S_ / 128, B_), 256, 0, stream>>>(
      Qb, Kb, Es, nullptr, nullptr, nullptr, nullptr, nullptr,
      D_, D_, D_, S_,
      (long)S_ * D_, (long)S_ * D_, (long)S_ * S_, 1.0f / sqrtf((float)D_));
  // O[b,q,e] = (Es[b] @ V[b]) / rowsum  -> fp32
  // 128x64 blocks -> (12, 16, 4) = 768 blocks = exactly 3/CU (was 1.5/CU)
  gemm_bt<3, 4, 2><<<dim3(D_ / 64, S_ / 128, B_), 256, 0, stream>>>(
      Es, Vt, out, nullptr, nullptr, nullptr, nullptr, nullptr,
      S_, S_, MS, D_,
      (long)S_ * S_, (long)S_, (long)S_ * D_, 1.0f);
}